// Round 1
// baseline (207.275 us; speedup 1.0000x reference)
//
#include <hip/hip_runtime.h>
#include <math.h>

// YOLO loss — low-LDS latency-hiding version.
// Theory (R-this): previous kernel was latency-bound (VALUBusy 12%, HBM 15%,
// occupancy 40%). Full 30-f32/cell staging cost 7.7 KB LDS *per wave*
// (caps CU at 20 waves) and the block-wide __syncthreads convoyed waves.
// Now: one coalesced float2 sweep over pred both (a) stages ONLY the 10 box
// floats to wave-private LDS (2.5 KB/wave) and (b) computes class loss
// directly from global (tcls addresses come out contiguous). Wave-local
// s_waitcnt replaces the block barrier; mask/tbox loads hoisted.
// __launch_bounds__(256,8) caps VGPR at 64 -> 32 waves/CU possible.

#define BLOCK 256
#define WPB 4            // waves per block
#define CPW 64           // cells per wave

__global__ __launch_bounds__(BLOCK, 8) void k_yolo(
    const float*  __restrict__ pred,
    const float4* __restrict__ tbox4,
    const float2* __restrict__ tcls2,
    const int*    __restrict__ mask,
    float4*       __restrict__ partial,
    int n_cells)
{
    __shared__ float2 sbox[WPB][CPW * 5];   // box floats only: 10240 B/block
    const int tid  = threadIdx.x;
    const int lane = tid & 63;
    const int w    = tid >> 6;
    const long long cell0 = ((long long)blockIdx.x * WPB + w) * CPW;

    long long rem = (long long)n_cells - cell0;
    int lim = rem < 0 ? 0 : (rem > CPW ? CPW : (int)rem);   // cells in this tile

    float cls = 0.f, noobj = 0.f, reg = 0.f, cont = 0.f;

    // hoisted loads: issue early, consumed late
    int mflag = 0;
    float4 tb = make_float4(0.f, 0.f, 0.f, 0.f);
    if (lane < lim) {
        mflag = mask[cell0 + lane];
        tb    = tbox4[cell0 + lane];
    }

    const float2* p2  = reinterpret_cast<const float2*>(pred) + cell0 * 15;
    const float2* t2  = tcls2 + cell0 * 10;
    float2*       sb2 = sbox[w];

    // ---- single coalesced sweep over the wave's 960 pred float2s ----
    // j = 15*c + r (float2 units). r<5: box pair -> LDS. r>=5: class pair;
    // matching tcls float2 index is c*10 + (r-5), which is CONTIGUOUS in j.
    #pragma unroll
    for (int k = 0; k < 15; ++k) {
        int j = lane + (k << 6);          // 0..959
        int c = j / 15;                   // local cell 0..63 (magic-mul div)
        int r = j - c * 15;               // 0..14
        int mc = __shfl(mflag, c, 64);    // mask of the cell this pair belongs to
        if (c < lim) {
            float2 v = p2[j];
            if (r < 5) {
                sb2[c * 5 + r] = v;       // stage box floats (wave-private)
            } else if (mc) {
                float2 t = t2[c * 10 + (r - 5)];
                float d0 = t.x - v.x, d1 = t.y - v.y;
                cls = fmaf(d0, d0, cls);
                cls = fmaf(d1, d1, cls);
            }
        }
    }

    // wave-local visibility: sbox[w] is written/read by this wave only, so a
    // full block barrier is unnecessary — just drain our own LDS writes.
    asm volatile("s_waitcnt lgkmcnt(0)" ::: "memory");
    __builtin_amdgcn_sched_barrier(0);

    // ---- per-lane box terms (read staged box floats) ----
    if (lane < lim) {
        const float2* bl = sb2 + lane * 5;
        float2 v0 = bl[0], v1 = bl[1], v2 = bl[2], v3 = bl[3], v4 = bl[4];
        // floats 0..9: box0 = (v0.x,v0.y,v1.x,v1.y, conf v2.x)
        //             box1 = (v2.y,v3.x,v3.y,v4.x, conf v4.y)
        if (mflag) {
            float txc = tb.x / 14.0f, tyc = tb.y / 14.0f;
            float t0 = txc - 0.5f * tb.z, t1 = tyc - 0.5f * tb.w;
            float t2c = txc + 0.5f * tb.z, t3 = tyc + 0.5f * tb.w;
            float area_t = (t2c - t0) * (t3 - t1);
            float bx[2] = { v0.x, v2.y }, by[2] = { v0.y, v3.x };
            float bw[2] = { v1.x, v3.y }, bh[2] = { v1.y, v4.x };
            float bcf[2] = { v2.x, v4.y };
            float iou[2];
            #pragma unroll
            for (int b = 0; b < 2; ++b) {
                float px = bx[b] / 14.0f, py = by[b] / 14.0f;
                float q0 = px - 0.5f * bw[b], q1 = py - 0.5f * bh[b];
                float q2 = px + 0.5f * bw[b], q3 = py + 0.5f * bh[b];
                float lt0 = fmaxf(t0, q0), lt1 = fmaxf(t1, q1);
                float rb0 = fminf(t2c, q2), rb1 = fminf(t3, q3);
                float ww = fmaxf(rb0 - lt0, 0.f), hh = fmaxf(rb1 - lt1, 0.f);
                float inter = ww * hh;
                float area_p = (q2 - q0) * (q3 - q1);
                iou[b] = inter / (area_t + area_p - inter);
            }
            int bi = (iou[1] > iou[0]) ? 1 : 0;   // first-max tie rule
            float dx = bx[bi] - tb.x, dy = by[bi] - tb.y;
            float swd = sqrtf(bw[bi]) - sqrtf(tb.z);
            float shd = sqrtf(bh[bi]) - sqrtf(tb.w);
            reg = 5.0f * (dx*dx + dy*dy + swd*swd + shd*shd);
            float dco = iou[bi] - bcf[bi];
            cont = dco * dco;
        } else {
            noobj = 0.5f * (v2.x * v2.x + v4.y * v4.y);
        }
    }

    // ---- wave shuffle reduce, then block reduce, store partial ----
    #pragma unroll
    for (int off = 32; off; off >>= 1) {
        cls   += __shfl_down(cls,   off, 64);
        noobj += __shfl_down(noobj, off, 64);
        reg   += __shfl_down(reg,   off, 64);
        cont  += __shfl_down(cont,  off, 64);
    }
    __shared__ float4 swr[WPB];
    if (lane == 0) swr[w] = make_float4(cls, noobj, reg, cont);
    __syncthreads();
    if (tid == 0) {
        float4 a = swr[0];
        #pragma unroll
        for (int i = 1; i < WPB; ++i) {
            float4 b = swr[i];
            a.x += b.x; a.y += b.y; a.z += b.z; a.w += b.w;
        }
        partial[blockIdx.x] = a;
    }
}

__global__ __launch_bounds__(BLOCK) void k_final(
    const float4* __restrict__ partial, int nblocks,
    float* __restrict__ out, float invN)
{
    float4 acc = make_float4(0.f, 0.f, 0.f, 0.f);
    for (int b = threadIdx.x; b < nblocks; b += BLOCK) {
        float4 v = partial[b];
        acc.x += v.x; acc.y += v.y; acc.z += v.z; acc.w += v.w;
    }
    #pragma unroll
    for (int off = 32; off; off >>= 1) {
        acc.x += __shfl_down(acc.x, off, 64);
        acc.y += __shfl_down(acc.y, off, 64);
        acc.z += __shfl_down(acc.z, off, 64);
        acc.w += __shfl_down(acc.w, off, 64);
    }
    __shared__ float4 sw[WPB];
    int lane = threadIdx.x & 63, w = threadIdx.x >> 6;
    if (lane == 0) sw[w] = acc;
    __syncthreads();
    if (threadIdx.x == 0) {
        float cls = 0.f, noobj = 0.f, reg = 0.f, cont = 0.f;
        #pragma unroll
        for (int i = 0; i < WPB; ++i) {
            cls += sw[i].x; noobj += sw[i].y; reg += sw[i].z; cont += sw[i].w;
        }
        out[0] = (cls + noobj + reg + cont) * invN;
        out[1] = reg;
        out[2] = cont;
        out[3] = noobj;
        out[4] = cls;
    }
}

extern "C" void kernel_launch(void* const* d_in, const int* in_sizes, int n_in,
                              void* d_out, int out_size, void* d_ws, size_t ws_size,
                              hipStream_t stream) {
    const float*  pred  = (const float*)d_in[0];   // (N,14,14,30) f32
    const float4* tbox4 = (const float4*)d_in[1];  // (N,14,14,4)  f32
    const float2* tcls2 = (const float2*)d_in[2];  // (N,14,14,20) f32
    const int*    mask  = (const int*)d_in[3];     // (N,14,14)    int32 (verified R1)
    float* out = (float*)d_out;
    float4* partial = (float4*)d_ws;

    int n_cells = in_sizes[3];
    int N = in_sizes[0] / (14 * 14 * 30);
    int nblocks = (n_cells + BLOCK - 1) / BLOCK;   // BLOCK == WPB*CPW cells/block

    hipLaunchKernelGGL(k_yolo, dim3(nblocks), dim3(BLOCK), 0, stream,
                       pred, tbox4, tcls2, mask, partial, n_cells);
    hipLaunchKernelGGL(k_final, dim3(1), dim3(BLOCK), 0, stream,
                       partial, nblocks, out, 1.0f / (float)N);
}

// Round 2
// 200.240 us; speedup vs baseline: 1.0351x; 1.0351x over previous
//
#include <hip/hip_runtime.h>
#include <math.h>

// YOLO loss — DMA-staged (global_load_lds) version.
// Theory (R2): R0/R1 both stuck at ~2.6 TB/s effective because per-wave
// bytes-in-flight were tiny (VGPR-limited load pipelining; Little's law).
// Now the 7.68 KB pred tile per wave is staged by 8x global_load_lds
// dwordx4 (wave-private LDS, no VGPR cost, no block barrier — a single
// wave-local vmcnt drain), tcls is read per-lane-own-cell (no shfl/div),
// and mask/tbox are issued first. 30.7 KB LDS/block -> 5 blocks/CU.

#define BLOCK 256
#define WPB 4            // waves per block
#define CPW 64           // cells per wave

__global__ __launch_bounds__(BLOCK, 5) void k_yolo(
    const float*  __restrict__ pred,
    const float4* __restrict__ tbox4,
    const float4* __restrict__ tcls4,
    const int*    __restrict__ mask,
    float4*       __restrict__ partial,
    int n_cells)
{
    __shared__ float sp[WPB][CPW * 30];     // 30720 B/block
    const int tid  = threadIdx.x;
    const int lane = tid & 63;
    const int w    = tid >> 6;
    const long long cell0 = ((long long)blockIdx.x * WPB + w) * CPW;

    long long rem = (long long)n_cells - cell0;
    int lim = rem < 0 ? 0 : (rem > CPW ? CPW : (int)rem);

    float cls = 0.f, noobj = 0.f, reg = 0.f, cont = 0.f;

    // ---- oldest loads first: mask + tbox (consumed last) ----
    int mflag = 0;
    float4 tb = make_float4(0.f, 0.f, 0.f, 0.f);
    if (lane < lim) {
        mflag = mask[cell0 + lane];
        tb    = tbox4[cell0 + lane];
    }

    // ---- pred tile -> LDS via DMA: 480 float4 = 7x64 + 1x32, no VGPR cost ----
    if (lim == CPW) {
        const __attribute__((address_space(1))) float4* gp =
            (const __attribute__((address_space(1))) float4*)(pred + cell0 * 30);
        __attribute__((address_space(3))) float4* lp =
            (__attribute__((address_space(3))) float4*)(&sp[w][0]);
        #pragma unroll
        for (int i = 0; i < 7; ++i) {
            __builtin_amdgcn_global_load_lds(
                (const __attribute__((address_space(1))) void*)(gp + lane + i * 64),
                (__attribute__((address_space(3))) void*)(lp + i * 64),
                16, 0, 0);
        }
        if (lane < 32) {
            __builtin_amdgcn_global_load_lds(
                (const __attribute__((address_space(1))) void*)(gp + 448 + lane),
                (__attribute__((address_space(3))) void*)(lp + 448),
                16, 0, 0);
        }
    } else if (lim > 0) {
        // tail tile (not hit for N=4096 grid): guarded scalar staging
        const float* gsrc = pred + cell0 * 30;
        for (int k = lane; k < lim * 30; k += 64) sp[w][k] = gsrc[k];
    }

    // ---- tcls: per-lane-own-cell, 5 float4, only for masked cells ----
    float4 tc[5];
    if (mflag) {
        const float4* t4 = tcls4 + (cell0 + lane) * 5;
        #pragma unroll
        for (int q = 0; q < 5; ++q) tc[q] = t4[q];
    }

    // wave-local drain: DMA completion is tracked by vmcnt; LDS tile is
    // wave-private so no block barrier is needed. lgkmcnt covers the
    // tail-path ds_writes. sched_barrier pins following ds_reads (rule #18).
    asm volatile("s_waitcnt vmcnt(0) lgkmcnt(0)" ::: "memory");
    __builtin_amdgcn_sched_barrier(0);

    // ---- per-lane terms ----
    if (lane < lim) {
        const float2* pc2 = reinterpret_cast<const float2*>(sp[w] + lane * 30);
        float2 v0 = pc2[0], v1 = pc2[1], v2 = pc2[2], v3 = pc2[3], v4 = pc2[4];
        // floats 0..9: box0 = (v0.x,v0.y,v1.x,v1.y, conf v2.x)
        //              box1 = (v2.y,v3.x,v3.y,v4.x, conf v4.y)
        if (mflag) {
            float txc = tb.x / 14.0f, tyc = tb.y / 14.0f;
            float t0 = txc - 0.5f * tb.z, t1 = tyc - 0.5f * tb.w;
            float t2c = txc + 0.5f * tb.z, t3 = tyc + 0.5f * tb.w;
            float area_t = (t2c - t0) * (t3 - t1);
            float bx[2] = { v0.x, v2.y }, by[2] = { v0.y, v3.x };
            float bw[2] = { v1.x, v3.y }, bh[2] = { v1.y, v4.x };
            float bcf[2] = { v2.x, v4.y };
            float iou[2];
            #pragma unroll
            for (int b = 0; b < 2; ++b) {
                float px = bx[b] / 14.0f, py = by[b] / 14.0f;
                float q0 = px - 0.5f * bw[b], q1 = py - 0.5f * bh[b];
                float q2 = px + 0.5f * bw[b], q3 = py + 0.5f * bh[b];
                float lt0 = fmaxf(t0, q0), lt1 = fmaxf(t1, q1);
                float rb0 = fminf(t2c, q2), rb1 = fminf(t3, q3);
                float ww = fmaxf(rb0 - lt0, 0.f), hh = fmaxf(rb1 - lt1, 0.f);
                float inter = ww * hh;
                float area_p = (q2 - q0) * (q3 - q1);
                iou[b] = inter / (area_t + area_p - inter);
            }
            int bi = (iou[1] > iou[0]) ? 1 : 0;   // first-max tie rule
            float dx = bx[bi] - tb.x, dy = by[bi] - tb.y;
            float swd = sqrtf(bw[bi]) - sqrtf(tb.z);
            float shd = sqrtf(bh[bi]) - sqrtf(tb.w);
            reg = 5.0f * (dx*dx + dy*dy + swd*swd + shd*shd);
            float dco = iou[bi] - bcf[bi];
            cont = dco * dco;

            // class loss: tc[q] vs pred class floats 10+4q..13+4q (two float2s)
            #pragma unroll
            for (int q = 0; q < 5; ++q) {
                float2 a = pc2[5 + 2 * q];
                float2 b = pc2[6 + 2 * q];
                float d0 = tc[q].x - a.x, d1 = tc[q].y - a.y;
                float d2 = tc[q].z - b.x, d3 = tc[q].w - b.y;
                cls = fmaf(d0, d0, cls);
                cls = fmaf(d1, d1, cls);
                cls = fmaf(d2, d2, cls);
                cls = fmaf(d3, d3, cls);
            }
        } else {
            noobj = 0.5f * (v2.x * v2.x + v4.y * v4.y);
        }
    }

    // ---- wave shuffle reduce, then block reduce, store partial ----
    #pragma unroll
    for (int off = 32; off; off >>= 1) {
        cls   += __shfl_down(cls,   off, 64);
        noobj += __shfl_down(noobj, off, 64);
        reg   += __shfl_down(reg,   off, 64);
        cont  += __shfl_down(cont,  off, 64);
    }
    __shared__ float4 swr[WPB];
    if (lane == 0) swr[w] = make_float4(cls, noobj, reg, cont);
    __syncthreads();
    if (tid == 0) {
        float4 a = swr[0];
        #pragma unroll
        for (int i = 1; i < WPB; ++i) {
            float4 b = swr[i];
            a.x += b.x; a.y += b.y; a.z += b.z; a.w += b.w;
        }
        partial[blockIdx.x] = a;
    }
}

__global__ __launch_bounds__(BLOCK) void k_final(
    const float4* __restrict__ partial, int nblocks,
    float* __restrict__ out, float invN)
{
    float4 acc = make_float4(0.f, 0.f, 0.f, 0.f);
    for (int b = threadIdx.x; b < nblocks; b += BLOCK) {
        float4 v = partial[b];
        acc.x += v.x; acc.y += v.y; acc.z += v.z; acc.w += v.w;
    }
    #pragma unroll
    for (int off = 32; off; off >>= 1) {
        acc.x += __shfl_down(acc.x, off, 64);
        acc.y += __shfl_down(acc.y, off, 64);
        acc.z += __shfl_down(acc.z, off, 64);
        acc.w += __shfl_down(acc.w, off, 64);
    }
    __shared__ float4 sw[WPB];
    int lane = threadIdx.x & 63, w = threadIdx.x >> 6;
    if (lane == 0) sw[w] = acc;
    __syncthreads();
    if (threadIdx.x == 0) {
        float cls = 0.f, noobj = 0.f, reg = 0.f, cont = 0.f;
        #pragma unroll
        for (int i = 0; i < WPB; ++i) {
            cls += sw[i].x; noobj += sw[i].y; reg += sw[i].z; cont += sw[i].w;
        }
        out[0] = (cls + noobj + reg + cont) * invN;
        out[1] = reg;
        out[2] = cont;
        out[3] = noobj;
        out[4] = cls;
    }
}

extern "C" void kernel_launch(void* const* d_in, const int* in_sizes, int n_in,
                              void* d_out, int out_size, void* d_ws, size_t ws_size,
                              hipStream_t stream) {
    const float*  pred  = (const float*)d_in[0];   // (N,14,14,30) f32
    const float4* tbox4 = (const float4*)d_in[1];  // (N,14,14,4)  f32
    const float4* tcls4 = (const float4*)d_in[2];  // (N,14,14,20) f32
    const int*    mask  = (const int*)d_in[3];     // (N,14,14)    int32
    float* out = (float*)d_out;
    float4* partial = (float4*)d_ws;

    int n_cells = in_sizes[3];
    int N = in_sizes[0] / (14 * 14 * 30);
    int nblocks = (n_cells + BLOCK - 1) / BLOCK;   // BLOCK == WPB*CPW cells/block

    hipLaunchKernelGGL(k_yolo, dim3(nblocks), dim3(BLOCK), 0, stream,
                       pred, tbox4, tcls4, mask, partial, n_cells);
    hipLaunchKernelGGL(k_final, dim3(1), dim3(BLOCK), 0, stream,
                       partial, nblocks, out, 1.0f / (float)N);
}